// Round 1
// baseline (985.801 us; speedup 1.0000x reference)
//
#include <hip/hip_runtime.h>
#include <hip/hip_bf16.h>

// Problem: VQ quantize. input [8,64,64,256] f32 -> flatten [M=32768, K=256]
// embed [K=256, N=4096] f32. Outputs concatenated in d_out (f32):
//   quantize [8388608], diff [1], embed_ind [32768] (as float)

#define M_ROWS 32768
#define K_DIM 256
#define N_CODES 4096

#define BM 128
#define BN 128
#define BK 32
#define TM 8
#define TN 8

// ---------------- Kernel 0: code norms ||e_j||^2 ----------------
__global__ void norms_kernel(const float* __restrict__ E, float* __restrict__ norms) {
    int j = blockIdx.x * blockDim.x + threadIdx.x;  // 0..4095
    if (j >= N_CODES) return;
    float s = 0.f;
    for (int d = 0; d < K_DIM; ++d) {
        float v = E[(size_t)d * N_CODES + j];
        s = fmaf(v, v, s);
    }
    norms[j] = s;
}

// ---------------- Kernel 1: GEMM + fused argmin ----------------
// dist = ||e||^2 - 2 x.e  (||x||^2 constant per row, irrelevant for argmin)
__global__ __launch_bounds__(256, 2) void gemm_argmin_kernel(
    const float* __restrict__ F,     // [M][K]
    const float* __restrict__ E,     // [K][N]
    const float* __restrict__ norms, // [N]
    unsigned long long* __restrict__ keys)  // [M], pre-set to all-ones
{
    __shared__ float As[BK][BM + 4];  // transposed: [k][m]
    __shared__ float Bs[BK][BN + 4];

    const int bx = blockIdx.x & 31;        // N tile (32 tiles)
    const int by = blockIdx.x >> 5;        // M tile (256 tiles)
    const int bm0 = by * BM;
    const int bn0 = bx * BN;
    const int tid = threadIdx.x;
    const int tx = tid & 15;               // code direction
    const int ty = tid >> 4;               // row direction

    float acc[TM][TN];
#pragma unroll
    for (int i = 0; i < TM; ++i)
#pragma unroll
        for (int j = 0; j < TN; ++j) acc[i][j] = 0.f;

    for (int kc = 0; kc < K_DIM; kc += BK) {
        // --- stage: each thread loads 4 float4 of A and 4 float4 of B ---
        float4 a_reg[4], b_reg[4];
#pragma unroll
        for (int i = 0; i < 4; ++i) {
            int idx = tid + i * 256;
            int m  = idx >> 3, k4 = idx & 7;         // A: 128 rows x 8 float4
            a_reg[i] = *(const float4*)&F[(size_t)(bm0 + m) * K_DIM + kc + k4 * 4];
            int kk = idx >> 5, n4 = idx & 31;        // B: 32 k x 32 float4
            b_reg[i] = *(const float4*)&E[(size_t)(kc + kk) * N_CODES + bn0 + n4 * 4];
        }
        __syncthreads();   // previous compute done reading LDS
#pragma unroll
        for (int i = 0; i < 4; ++i) {
            int idx = tid + i * 256;
            int m  = idx >> 3, k4 = idx & 7;
            As[k4 * 4 + 0][m] = a_reg[i].x;
            As[k4 * 4 + 1][m] = a_reg[i].y;
            As[k4 * 4 + 2][m] = a_reg[i].z;
            As[k4 * 4 + 3][m] = a_reg[i].w;
            int kk = idx >> 5, n4 = idx & 31;
            *(float4*)&Bs[kk][n4 * 4] = b_reg[i];
        }
        __syncthreads();

        // --- compute 32 k-steps, 8x8 micro-tile ---
#pragma unroll
        for (int k = 0; k < BK; ++k) {
            float a[TM], b[TN];
            *(float4*)&a[0] = *(const float4*)&As[k][ty * TM];
            *(float4*)&a[4] = *(const float4*)&As[k][ty * TM + 4];
            *(float4*)&b[0] = *(const float4*)&Bs[k][tx * TN];
            *(float4*)&b[4] = *(const float4*)&Bs[k][tx * TN + 4];
#pragma unroll
            for (int i = 0; i < TM; ++i)
#pragma unroll
                for (int j = 0; j < TN; ++j)
                    acc[i][j] = fmaf(a[i], b[j], acc[i][j]);
        }
    }

    // --- epilogue: per-row argmin over this block's 128 codes ---
    float nrm[TN];
#pragma unroll
    for (int j = 0; j < TN; ++j) nrm[j] = norms[bn0 + tx * TN + j];

#pragma unroll
    for (int i = 0; i < TM; ++i) {
        float best = INFINITY;
        int bestj = 0;
#pragma unroll
        for (int j = 0; j < TN; ++j) {
            float d = fmaf(-2.f, acc[i][j], nrm[j]);
            if (d < best) { best = d; bestj = bn0 + tx * TN + j; }
        }
        // ordered-float encoding so u64 compare == float compare
        unsigned u = __float_as_uint(best);
        u = (u & 0x80000000u) ? ~u : (u | 0x80000000u);
        unsigned long long key = ((unsigned long long)u << 32) | (unsigned)bestj;
        // reduce across the 16 lanes sharing ty (lanes differ only in tx bits 0..3)
#pragma unroll
        for (int s = 1; s < 16; s <<= 1) {
            unsigned long long o = __shfl_xor(key, s, 64);
            if (o < key) key = o;
        }
        if (tx == 0) atomicMin(&keys[bm0 + ty * TM + i], key);
    }
}

// ---------------- Kernel 2: gather + STE + diff + indices ----------------
__global__ void gather_kernel(
    const float* __restrict__ F,             // [M][K]
    const float* __restrict__ E,             // [K][N]
    const unsigned long long* __restrict__ keys,  // [M]
    float* __restrict__ q_out,               // [M][K]
    float* __restrict__ diff_out,            // [1] (pre-zeroed)
    float* __restrict__ ind_out)             // [M] (as float)
{
    const int lane = threadIdx.x & 63;
    const int wave = (blockIdx.x * (blockDim.x >> 6)) + (threadIdx.x >> 6);
    const int nwaves = gridDim.x * (blockDim.x >> 6);

    float dsum = 0.f;
    for (int row = wave; row < M_ROWS; row += nwaves) {
        unsigned long long key = keys[row];
        int ind = (int)(key & 0xFFFFFFFFull);
        if (lane == 0) ind_out[row] = (float)ind;
#pragma unroll
        for (int t = 0; t < 4; ++t) {
            int d = lane + t * 64;
            float x = F[(size_t)row * K_DIM + d];
            float q = E[(size_t)d * N_CODES + ind];
            float delta = q - x;
            q_out[(size_t)row * K_DIM + d] = x + delta;  // STE, same rounding as ref
            dsum = fmaf(delta, delta, dsum);
        }
    }
    // wave reduce
#pragma unroll
    for (int s = 32; s >= 1; s >>= 1) dsum += __shfl_xor(dsum, s, 64);
    if (lane == 0)
        atomicAdd(diff_out, dsum * (1.0f / ((float)M_ROWS * (float)K_DIM)));
}

extern "C" void kernel_launch(void* const* d_in, const int* in_sizes, int n_in,
                              void* d_out, int out_size, void* d_ws, size_t ws_size,
                              hipStream_t stream) {
    const float* F = (const float*)d_in[0];   // input  [8,64,64,256]
    const float* E = (const float*)d_in[1];   // embed  [256,4096]

    float* q_out    = (float*)d_out;                        // [8388608]
    float* diff_out = (float*)d_out + (size_t)M_ROWS * K_DIM;  // [1]
    float* ind_out  = diff_out + 1;                         // [32768] as float

    float* norms = (float*)d_ws;                                   // 16 KB
    unsigned long long* keys = (unsigned long long*)((char*)d_ws + 16384); // 256 KB

    // keys must start at max (ws is poisoned 0xAA which is NOT max for our encoding)
    hipMemsetAsync(keys, 0xFF, (size_t)M_ROWS * 8, stream);
    // diff accumulator must start at 0 (d_out poisoned 0xAA)
    hipMemsetAsync(diff_out, 0, 4, stream);

    norms_kernel<<<N_CODES / 256, 256, 0, stream>>>(E, norms);
    gemm_argmin_kernel<<<(M_ROWS / BM) * (N_CODES / BN), 256, 0, stream>>>(F, E, norms, keys);
    gather_kernel<<<1024, 256, 0, stream>>>(F, E, keys, q_out, diff_out, ind_out);
}